// Round 9
// baseline (284.589 us; speedup 1.0000x reference)
//
#include <hip/hip_runtime.h>

#define B_ 4
#define CK 64
#define CV 512
#define HW_ 900
#define THW 7200
#define MT 96
#define QB 64
#define CVB 128
#define NS 3             // m-splits
#define MSPL (THW / NS)  // 2400
#define NIT (MSPL / MT)  // 25
#define ETP 104          // e_t row stride in shorts (208B, keeps 16B-aligned b128 reads)

typedef __attribute__((ext_vector_type(4))) float f32x4;
typedef __attribute__((ext_vector_type(4))) float float4_;
typedef __attribute__((ext_vector_type(8))) short s16x8;
typedef __attribute__((ext_vector_type(4))) short s16x4;

__device__ __forceinline__ short f2bf(float f) {
  union { float f; unsigned u; } x; x.f = f;
  unsigned u = x.u;
  return (short)((u + 0x7fffu + ((u >> 16) & 1u)) >> 16);  // RNE to bf16
}

// Fused prep: [A] mk->mkT bf16 + asq  [B] qk->bf16*0.25*log2e  [C] mv->bf16  [D] qv->out
#define NBLK_A 113
#define NBLK_B 900
#define NBLK_C 14400
#define NBLK_D 1800
__global__ __launch_bounds__(256) void prep_kernel(const float* __restrict__ mk,
                                                   const float* __restrict__ qk,
                                                   const float* __restrict__ mv,
                                                   const float* __restrict__ qv,
                                                   short* __restrict__ mkT,
                                                   short* __restrict__ qkb,
                                                   short* __restrict__ mvb,
                                                   float* __restrict__ asq,
                                                   float* __restrict__ out) {
  int bid = blockIdx.x;
  if (bid < NBLK_A) {  // mk transpose + |a|^2
    int idx = bid * 256 + threadIdx.x;
    if (idx >= B_ * THW) return;
    int b = idx / THW, m = idx - b * THW;
    const float* src = mk + (size_t)b * CK * THW + m;
    short row[CK];
    float acc = 0.f;
#pragma unroll
    for (int k = 0; k < CK; ++k) {
      float v = src[(size_t)k * THW];
      acc += v * v;
      row[k] = f2bf(v);
    }
    short* dst = mkT + (size_t)idx * CK;
#pragma unroll
    for (int c = 0; c < CK / 8; ++c)
      *reinterpret_cast<s16x8*>(dst + c * 8) = *reinterpret_cast<s16x8*>(row + c * 8);
    asq[idx] = acc * 0.18033688011112042f;  // 0.125 * log2(e)
  } else if (bid < NBLK_A + NBLK_B) {  // qk cast (exp2-units scale folded)
    int i = (bid - NBLK_A) * 256 + threadIdx.x;
    if (i < B_ * CK * HW_) qkb[i] = f2bf(qk[i] * 0.36067376022224085f);
  } else if (bid < NBLK_A + NBLK_B + NBLK_C) {  // mv cast
    int i = (bid - (NBLK_A + NBLK_B)) * 256 + threadIdx.x;
    float4_ v = reinterpret_cast<const float4_*>(mv)[i];
    s16x4 o;
    o[0] = f2bf(v[0]); o[1] = f2bf(v[1]); o[2] = f2bf(v[2]); o[3] = f2bf(v[3]);
    *reinterpret_cast<s16x4*>(mvb + (size_t)i * 4) = o;
  } else {  // qv passthrough -> out channels [CV, 2CV)
    int i = (bid - (NBLK_A + NBLK_B + NBLK_C)) * 256 + threadIdx.x;
    const int perb = CV * HW_ / 4;
    int b = i / perb, r = i - b * perb;
    float4_ v = reinterpret_cast<const float4_*>(qv)[i];
    *reinterpret_cast<float4_*>(out + (size_t)b * 2 * CV * HW_ + CV * HW_ + (size_t)r * 4) = v;
  }
}

// Attention over one m-split. cv-split waves: wave w owns cv [w*32, w*32+32) x all 64 q.
// mk, mv, asq fragments come straight from global (L1/L2-resident); LDS holds only E.
// grid (15 qb, 4 cvc * NS splits, B). Writes unnormalized partial numerator + denom.
__global__ __launch_bounds__(256, 4) void attn_kernel(const short* __restrict__ mkT,
                                                      const short* __restrict__ qkb,
                                                      const short* __restrict__ mvb,
                                                      const float* __restrict__ asq,
                                                      float* __restrict__ part,
                                                      float* __restrict__ denomp) {
  __shared__ short e_t[64][ETP];  // 13,312 B — the only LDS

  const int tid = threadIdx.x;
  const int wave = tid >> 6, lane = tid & 63;
  const int g = lane >> 4, c = lane & 15;
  const int qb = blockIdx.x;
  const int cvc = blockIdx.y & 3, s = blockIdx.y >> 2;
  const int b = blockIdx.z;
  const int q = qb * QB + wave * 16 + c;  // this lane's logits q

  // hoist qk B-frags: lane holds B[k = ks*32 + g*8 + j][n = q]
  s16x8 qkf[2];
  {
    const short* qs = qkb + (size_t)b * CK * HW_;
#pragma unroll
    for (int ks = 0; ks < 2; ++ks)
#pragma unroll
      for (int j = 0; j < 8; ++j)
        qkf[ks][j] = (q < HW_) ? qs[(size_t)(ks * 32 + g * 8 + j) * HW_ + q] : (short)0;
  }

  f32x4 acc[2][4];  // [af over cv][qf over q]
#pragma unroll
  for (int i = 0; i < 2; ++i)
#pragma unroll
    for (int j = 0; j < 4; ++j) acc[i][j] = (f32x4){0.f, 0.f, 0.f, 0.f};
  float denom = 0.f;

  const short* mkb = mkT + (size_t)b * THW * CK;
  const short* mvB = mvb + ((size_t)b * CV + cvc * CVB + wave * 32) * THW;  // wave's cv rows
  const float* asb = asq + (size_t)b * THW;

  for (int it = 0; it < NIT; ++it) {
    const int m0 = s * MSPL + it * MT;

    // preload this iter's mv A-frags (registers; issued early, consumed after barrier)
    s16x8 mvf[2][3];
#pragma unroll
    for (int af = 0; af < 2; ++af)
#pragma unroll
      for (int ks = 0; ks < 3; ++ks)
        mvf[af][ks] = *reinterpret_cast<const s16x8*>(
            mvB + (size_t)(af * 16 + c) * THW + m0 + ks * 32 + g * 8);

    // logits: S = mk(96m x 64k) x qk(64k x 16q), E = exp2(S - asq) -> LDS
#pragma unroll
    for (int mf = 0; mf < 6; ++mf) {
      f32x4 sa = (f32x4){0.f, 0.f, 0.f, 0.f};
#pragma unroll
      for (int ks = 0; ks < 2; ++ks) {
        s16x8 a = *reinterpret_cast<const s16x8*>(
            mkb + (size_t)(m0 + mf * 16 + c) * CK + ks * 32 + g * 8);
        sa = __builtin_amdgcn_mfma_f32_16x16x32_bf16(a, qkf[ks], sa, 0, 0, 0);
      }
      f32x4 av = *reinterpret_cast<const f32x4*>(asb + m0 + mf * 16 + g * 4);
      s16x4 e4;
#pragma unroll
      for (int r = 0; r < 4; ++r) {
        float e = exp2f(sa[r] - av[r]);
        denom += e;
        union { float f; unsigned u; } cu; cu.f = e;
        e4[r] = (short)(cu.u >> 16);  // truncate to bf16 (cheap; error cancels in ratio)
      }
      *reinterpret_cast<s16x4*>(&e_t[wave * 16 + c][mf * 16 + g * 4]) = e4;
    }
    __syncthreads();

    // readout: acc[32cv x 64q] += mv(32cv x 96m) x E(96m x 64q)
#pragma unroll
    for (int ks = 0; ks < 3; ++ks) {
      s16x8 ef[4];
#pragma unroll
      for (int qf = 0; qf < 4; ++qf)
        ef[qf] = *reinterpret_cast<const s16x8*>(&e_t[qf * 16 + c][ks * 32 + g * 8]);
#pragma unroll
      for (int af = 0; af < 2; ++af)
#pragma unroll
        for (int qf = 0; qf < 4; ++qf)
          acc[af][qf] =
              __builtin_amdgcn_mfma_f32_16x16x32_bf16(mvf[af][ks], ef[qf], acc[af][qf], 0, 0, 0);
    }
    __syncthreads();  // WAR: next iter's e-writes vs this iter's e-reads
  }

  // denom: combine the 4 lane-groups (same q, disjoint m)
  denom += __shfl_xor(denom, 16);
  denom += __shfl_xor(denom, 32);
  if (cvc == 0 && lane < 16)
    denomp[((size_t)s * B_ + b) * 960 + qb * QB + wave * 16 + lane] = denom;

  // partial numerator: [block][cv_local 128][q_local 64]
  float* pb = part + (size_t)(((s * B_ + b) * 4 + cvc) * 15 + qb) * 8192;
#pragma unroll
  for (int af = 0; af < 2; ++af)
#pragma unroll
    for (int qf = 0; qf < 4; ++qf)
#pragma unroll
      for (int r = 0; r < 4; ++r)
        pb[(size_t)(wave * 32 + af * 16 + g * 4 + r) * 64 + qf * 16 + c] = acc[af][qf][r];
}

// Sum NS partials, normalize, write mem half of out.
__global__ __launch_bounds__(256) void finalize_kernel(const float* __restrict__ part,
                                                       const float* __restrict__ denomp,
                                                       float* __restrict__ out) {
  int t = blockIdx.x * 256 + threadIdx.x;  // 491,520 threads
  int q4 = t & 15;
  int cvl = (t >> 4) & 127;
  int r1 = t >> 11;
  int qb = r1 % 15;
  int r2 = r1 / 15;
  int cvc = r2 & 3;
  int b = r2 >> 2;
  int q0 = qb * QB + q4 * 4;
  if (q0 >= HW_) return;
  const size_t sstr = (size_t)B_ * 4 * 15 * 8192;
  size_t base = (size_t)((b * 4 + cvc) * 15 + qb) * 8192 + cvl * 64 + q4 * 4;
  f32x4 p = *reinterpret_cast<const f32x4*>(part + base);
  f32x4 p1 = *reinterpret_cast<const f32x4*>(part + base + sstr);
  f32x4 p2 = *reinterpret_cast<const f32x4*>(part + base + 2 * sstr);
  p = p + p1 + p2;
  const float* dp = denomp + (size_t)b * 960 + q0;
  f32x4 d = *reinterpret_cast<const f32x4*>(dp) +
            *reinterpret_cast<const f32x4*>(dp + B_ * 960) +
            *reinterpret_cast<const f32x4*>(dp + 2 * B_ * 960);
  f32x4 o;
#pragma unroll
  for (int j = 0; j < 4; ++j) o[j] = p[j] / d[j];
  *reinterpret_cast<f32x4*>(out + (size_t)b * 2 * CV * HW_ +
                            (size_t)(cvc * CVB + cvl) * HW_ + q0) = o;
}

extern "C" void kernel_launch(void* const* d_in, const int* in_sizes, int n_in,
                              void* d_out, int out_size, void* d_ws, size_t ws_size,
                              hipStream_t stream) {
  const float* mk = (const float*)d_in[0];
  const float* qk = (const float*)d_in[1];
  const float* mv = (const float*)d_in[2];
  const float* qv = (const float*)d_in[3];
  float* out = (float*)d_out;

  // workspace layout (57,392,640 B total)
  char* ws = (char*)d_ws;
  short* mvb   = (short*)ws;                   // 29,491,200
  short* mkT   = (short*)(ws + 29491200);      //  3,686,400
  short* qkb   = (short*)(ws + 33177600);      //    460,800
  float* asq   = (float*)(ws + 33638400);      //    115,200
  float* denomp= (float*)(ws + 33753600);      //     46,080 (NS*B*960 f32)
  float* part  = (float*)(ws + 33799680);      // 23,592,960 (720 blocks * 128*64 f32)

  prep_kernel<<<dim3(NBLK_A + NBLK_B + NBLK_C + NBLK_D), dim3(256), 0, stream>>>(
      mk, qk, mv, qv, mkT, qkb, mvb, asq, out);
  attn_kernel<<<dim3(15, 4 * NS, B_), dim3(256), 0, stream>>>(mkT, qkb, mvb, asq, part, denomp);
  finalize_kernel<<<dim3(1920), dim3(256), 0, stream>>>(part, denomp, out);
}

// Round 10
// 261.217 us; speedup vs baseline: 1.0895x; 1.0895x over previous
//
#include <hip/hip_runtime.h>

#define B_ 4
#define CK 64
#define CV 512
#define HW_ 900
#define THW 7200
#define MT 96
#define QB 64
#define CVB 128
#define NS 3             // m-splits
#define MSPL (THW / NS)  // 2400
#define NIT (MSPL / MT)  // 25

typedef __attribute__((ext_vector_type(4))) float f32x4;
typedef __attribute__((ext_vector_type(4))) float float4_;
typedef __attribute__((ext_vector_type(8))) short s16x8;
typedef __attribute__((ext_vector_type(4))) short s16x4;

#define AS1 __attribute__((address_space(1)))
#define AS3 __attribute__((address_space(3)))
__device__ __forceinline__ void g2l16(const void* g, void* l) {
  __builtin_amdgcn_global_load_lds((const AS1 void*)g, (AS3 void*)l, 16, 0, 0);
}
__device__ __forceinline__ void g2l4(const void* g, void* l) {
  __builtin_amdgcn_global_load_lds((const AS1 void*)g, (AS3 void*)l, 4, 0, 0);
}

__device__ __forceinline__ short f2bf(float f) {
  union { float f; unsigned u; } x; x.f = f;
  unsigned u = x.u;
  return (short)((u + 0x7fffu + ((u >> 16) & 1u)) >> 16);  // RNE to bf16
}

// Fused prep: [A] mk->mkT bf16 + asq  [B] qk->bf16*0.25*log2e  [C] mv->bf16  [D] qv->out
#define NBLK_A 113
#define NBLK_B 900
#define NBLK_C 14400
#define NBLK_D 1800
__global__ __launch_bounds__(256) void prep_kernel(const float* __restrict__ mk,
                                                   const float* __restrict__ qk,
                                                   const float* __restrict__ mv,
                                                   const float* __restrict__ qv,
                                                   short* __restrict__ mkT,
                                                   short* __restrict__ qkb,
                                                   short* __restrict__ mvb,
                                                   float* __restrict__ asq,
                                                   float* __restrict__ out) {
  int bid = blockIdx.x;
  if (bid < NBLK_A) {  // mk transpose + |a|^2
    int idx = bid * 256 + threadIdx.x;
    if (idx >= B_ * THW) return;
    int b = idx / THW, m = idx - b * THW;
    const float* src = mk + (size_t)b * CK * THW + m;
    short row[CK];
    float acc = 0.f;
#pragma unroll
    for (int k = 0; k < CK; ++k) {
      float v = src[(size_t)k * THW];
      acc += v * v;
      row[k] = f2bf(v);
    }
    short* dst = mkT + (size_t)idx * CK;
#pragma unroll
    for (int c = 0; c < CK / 8; ++c)
      *reinterpret_cast<s16x8*>(dst + c * 8) = *reinterpret_cast<s16x8*>(row + c * 8);
    asq[idx] = acc * 0.18033688011112042f;  // 0.125 * log2(e)
  } else if (bid < NBLK_A + NBLK_B) {  // qk cast (exp2-units scale folded)
    int i = (bid - NBLK_A) * 256 + threadIdx.x;
    if (i < B_ * CK * HW_) qkb[i] = f2bf(qk[i] * 0.36067376022224085f);
  } else if (bid < NBLK_A + NBLK_B + NBLK_C) {  // mv cast
    int i = (bid - (NBLK_A + NBLK_B)) * 256 + threadIdx.x;
    float4_ v = reinterpret_cast<const float4_*>(mv)[i];
    s16x4 o;
    o[0] = f2bf(v[0]); o[1] = f2bf(v[1]); o[2] = f2bf(v[2]); o[3] = f2bf(v[3]);
    *reinterpret_cast<s16x4*>(mvb + (size_t)i * 4) = o;
  } else {  // qv passthrough -> out channels [CV, 2CV)
    int i = (bid - (NBLK_A + NBLK_B + NBLK_C)) * 256 + threadIdx.x;
    const int perb = CV * HW_ / 4;
    int b = i / perb, r = i - b * perb;
    float4_ v = reinterpret_cast<const float4_*>(qv)[i];
    *reinterpret_cast<float4_*>(out + (size_t)b * 2 * CV * HW_ + CV * HW_ + (size_t)r * 4) = v;
  }
}

// Fused attention, 2-phase gload_lds pipeline, ONE barrier/iter (e_t wave-private).
// q-split waves: wave w owns q-slice [w*16, w*16+16) x all 128 cv.
// LDS: mv/mk/asq double-buffered, XOR-swizzled (pre-swizzled global source).
// grid (15 qb, 4 cvc * NS s, B). Writes unnormalized partial numerator + denom.
__global__ __launch_bounds__(256, 1) void attn_kernel(const short* __restrict__ mkT,
                                                      const short* __restrict__ qkb,
                                                      const short* __restrict__ mvb,
                                                      const float* __restrict__ asq,
                                                      float* __restrict__ part,
                                                      float* __restrict__ denomp) {
  __shared__ __align__(16) short mvt[2][CVB][128];  // 256B rows, XOR (row&15)<<4 : 65,536 B
  __shared__ __align__(16) short mkt[2][MT][64];    // 128B rows, XOR (row&7)<<4  : 24,576 B
  __shared__ __align__(16) short et[4][16][128];    // 256B rows, XOR (row&15)<<4 : 16,384 B
  __shared__ __align__(16) float asqt[2][MT];       //                                768 B

  const int tid = threadIdx.x;
  const int wave = tid >> 6, lane = tid & 63;
  const int g = lane >> 4, c = lane & 15;
  const int qb = blockIdx.x;
  const int cvc = blockIdx.y & 3, s = blockIdx.y >> 2;
  const int b = blockIdx.z;
  const int q = qb * QB + wave * 16 + c;

  const short* mkb = mkT + (size_t)b * THW * CK;
  const short* mvsrc = mvb + ((size_t)b * CV + cvc * CVB) * THW;
  const float* asb = asq + (size_t)b * THW;

  // hoist qk B-frags: lane holds B[k = ks*32 + g*8 + j][n = q]
  s16x8 qkf[2];
  {
    const short* qs = qkb + (size_t)b * CK * HW_;
#pragma unroll
    for (int ks = 0; ks < 2; ++ks)
#pragma unroll
      for (int j = 0; j < 8; ++j)
        qkf[ks][j] = (q < HW_) ? qs[(size_t)(ks * 32 + g * 8 + j) * HW_ + q] : (short)0;
  }

  f32x4 acc[8];
#pragma unroll
  for (int i = 0; i < 8; ++i) acc[i] = (f32x4){0.f, 0.f, 0.f, 0.f};
  float denom = 0.f;

  // stage tile t into buffer nb (inverse-swizzled global source, linear LDS dest)
  auto STAGE = [&](int t, int nb) {
    const int m0 = s * MSPL + t * MT;
    // mv tile: 128 rows x 256B (192B valid + swizzle spill; over-read stays in ws)
#pragma unroll
    for (int p = 0; p < 8; ++p) {
      int ch = p * 256 + tid;
      int row = ch >> 4, sl = ch & 15;
      int so = (sl * 16) ^ ((row & 15) << 4);  // source byte offset within row
      g2l16(mvsrc + (size_t)row * THW + m0 + (so >> 1), (short*)mvt[nb] + ch * 8);
    }
    // mk tile: 96 rows x 128B
#pragma unroll
    for (int p = 0; p < 3; ++p) {
      int ch = p * 256 + tid;
      int row = ch >> 3, sl = ch & 7;
      int so = (sl * 16) ^ ((row & 7) << 4);
      g2l16(mkb + (size_t)(m0 + row) * CK + (so >> 1), (short*)mkt[nb] + ch * 8);
    }
    if (tid < MT) g2l4(asb + m0 + tid, &asqt[nb][tid]);
  };

  STAGE(0, 0);
  __syncthreads();

  for (int it = 0; it < NIT; ++it) {
    const int pb = it & 1, nb = pb ^ 1;
    if (it + 1 < NIT) STAGE(it + 1, nb);  // async: drains at end-of-iter barrier

    // logits: S = mk(96m x 64k) x qk(64k x 16q); E = exp2(S - asq) -> et (wave-private)
#pragma unroll
    for (int mf = 0; mf < 6; ++mf) {
      f32x4 sa = (f32x4){0.f, 0.f, 0.f, 0.f};
#pragma unroll
      for (int ks = 0; ks < 2; ++ks) {
        int cb = (ks * 64 + g * 16) ^ ((c & 7) << 4);
        s16x8 a = *reinterpret_cast<const s16x8*>(&mkt[pb][mf * 16 + c][cb >> 1]);
        sa = __builtin_amdgcn_mfma_f32_16x16x32_bf16(a, qkf[ks], sa, 0, 0, 0);
      }
      f32x4 av = *reinterpret_cast<const f32x4*>(&asqt[pb][mf * 16 + g * 4]);
      s16x4 e4;
#pragma unroll
      for (int r = 0; r < 4; ++r) {
        float e = exp2f(sa[r] - av[r]);
        denom += e;
        union { float f; unsigned u; } cu; cu.f = e;
        e4[r] = (short)(cu.u >> 16);  // truncate to bf16
      }
      int cbw = ((mf * 32 + g * 8) ^ ((c & 15) << 4)) >> 1;
      *reinterpret_cast<s16x4*>(&et[wave][c][cbw]) = e4;
    }

    // readout: acc(128cv x 16q) += mv(128cv x 96m) x E(96m x 16q); lgkmcnt orders et
#pragma unroll
    for (int ks = 0; ks < 3; ++ks) {
      int cb = ((ks * 64 + g * 16) ^ ((c & 15) << 4)) >> 1;  // shared by et & mvt (row&15==c&15)
      s16x8 bfr = *reinterpret_cast<const s16x8*>(&et[wave][c][cb]);
#pragma unroll
      for (int cf = 0; cf < 8; ++cf) {
        s16x8 afr = *reinterpret_cast<const s16x8*>(&mvt[pb][cf * 16 + c][cb]);
        acc[cf] = __builtin_amdgcn_mfma_f32_16x16x32_bf16(afr, bfr, acc[cf], 0, 0, 0);
      }
    }
    __syncthreads();  // drains stage(t+1) + protects buf[pb] WAR + et WAR
  }

  // denom: combine the 4 lane-groups (same q, disjoint m)
  denom += __shfl_xor(denom, 16);
  denom += __shfl_xor(denom, 32);
  if (cvc == 0 && lane < 16)
    denomp[((size_t)s * B_ + b) * 960 + qb * QB + wave * 16 + lane] = denom;

  // partial numerator: [block][cv_local 128][q_local 64]
  float* pb0 = part + (size_t)(((s * B_ + b) * 4 + cvc) * 15 + qb) * 8192 + wave * 16 + c;
#pragma unroll
  for (int cf = 0; cf < 8; ++cf)
#pragma unroll
    for (int r = 0; r < 4; ++r)
      pb0[(size_t)(cf * 16 + g * 4 + r) * 64] = acc[cf][r];
}

// Sum NS partials, normalize, write mem half of out.
__global__ __launch_bounds__(256) void finalize_kernel(const float* __restrict__ part,
                                                       const float* __restrict__ denomp,
                                                       float* __restrict__ out) {
  int t = blockIdx.x * 256 + threadIdx.x;  // 491,520 threads
  int q4 = t & 15;
  int cvl = (t >> 4) & 127;
  int r1 = t >> 11;
  int qb = r1 % 15;
  int r2 = r1 / 15;
  int cvc = r2 & 3;
  int b = r2 >> 2;
  int q0 = qb * QB + q4 * 4;
  if (q0 >= HW_) return;
  const size_t sstr = (size_t)B_ * 4 * 15 * 8192;
  size_t base = (size_t)((b * 4 + cvc) * 15 + qb) * 8192 + cvl * 64 + q4 * 4;
  f32x4 p = *reinterpret_cast<const f32x4*>(part + base);
  f32x4 p1 = *reinterpret_cast<const f32x4*>(part + base + sstr);
  f32x4 p2 = *reinterpret_cast<const f32x4*>(part + base + 2 * sstr);
  p = p + p1 + p2;
  const float* dp = denomp + (size_t)b * 960 + q0;
  f32x4 d = *reinterpret_cast<const f32x4*>(dp) +
            *reinterpret_cast<const f32x4*>(dp + B_ * 960) +
            *reinterpret_cast<const f32x4*>(dp + 2 * B_ * 960);
  f32x4 o;
#pragma unroll
  for (int j = 0; j < 4; ++j) o[j] = p[j] / d[j];
  *reinterpret_cast<f32x4*>(out + (size_t)b * 2 * CV * HW_ +
                            (size_t)(cvc * CVB + cvl) * HW_ + q0) = o;
}

extern "C" void kernel_launch(void* const* d_in, const int* in_sizes, int n_in,
                              void* d_out, int out_size, void* d_ws, size_t ws_size,
                              hipStream_t stream) {
  const float* mk = (const float*)d_in[0];
  const float* qk = (const float*)d_in[1];
  const float* mv = (const float*)d_in[2];
  const float* qv = (const float*)d_in[3];
  float* out = (float*)d_out;

  // workspace layout (57,392,640 B total)
  char* ws = (char*)d_ws;
  short* mvb   = (short*)ws;                   // 29,491,200
  short* mkT   = (short*)(ws + 29491200);      //  3,686,400
  short* qkb   = (short*)(ws + 33177600);      //    460,800
  float* asq   = (float*)(ws + 33638400);      //    115,200
  float* denomp= (float*)(ws + 33753600);      //     46,080 (NS*B*960 f32)
  float* part  = (float*)(ws + 33799680);      // 23,592,960 (720 blocks * 128*64 f32)

  prep_kernel<<<dim3(NBLK_A + NBLK_B + NBLK_C + NBLK_D), dim3(256), 0, stream>>>(
      mk, qk, mv, qv, mkT, qkb, mvb, asq, out);
  attn_kernel<<<dim3(15, 4 * NS, B_), dim3(256), 0, stream>>>(mkT, qkb, mvb, asq, part, denomp);
  finalize_kernel<<<dim3(1920), dim3(256), 0, stream>>>(part, denomp, out);
}